// Round 1
// baseline (267.959 us; speedup 1.0000x reference)
//
#include <hip/hip_runtime.h>
#include <hip/hip_bf16.h>
#include <stdint.h>

#define BATCH 8
#define SEQN  4096
#define DIM   128
#define QBLK  64
#define KVBLK 64
#define NWAVE 4

// Vt row stride in elements: 64 kv + 4 pad = 68 (136 B rows, 8B aligned -> b64 reads)
#define VT_S 68
// P row stride: 64 + 8 pad = 72 (144 B rows, 16B aligned -> b128 reads)
#define P_S  72

typedef __attribute__((ext_vector_type(4))) float  f32x4;
typedef __bf16 bf16x8 __attribute__((ext_vector_type(8)));

__device__ __forceinline__ ushort f2b(float x) {
  union { float f; uint32_t u; } a; a.f = x;
  uint32_t r = a.u + 0x7fffu + ((a.u >> 16) & 1u);   // RNE
  return (ushort)(r >> 16);
}

// One wave per row: rnorm + bf16 casts. K' = qk * rnorm * log2(e)/sqrt(d)
__global__ __launch_bounds__(256) void prep_kernel(
    const float* __restrict__ qk, const float* __restrict__ v,
    ushort* __restrict__ qb, ushort* __restrict__ kb, ushort* __restrict__ vb) {
  int row  = blockIdx.x * NWAVE + (threadIdx.x >> 6);
  int lane = threadIdx.x & 63;
  size_t off = (size_t)row * DIM + lane * 2;
  float2 q2 = *(const float2*)(qk + off);
  float2 v2 = *(const float2*)(v + off);
  float ss = q2.x * q2.x + q2.y * q2.y;
  #pragma unroll
  for (int m = 32; m; m >>= 1) ss += __shfl_xor(ss, m, 64);
  float nrm = sqrtf(ss);
  float r = 1.0f / fmaxf(nrm, 1e-12f);
  const float SC = 1.44269504088896340736f / 11.313708498984761f; // log2e/sqrt(128)
  float rs = r * SC;
  uint32_t qo = (uint32_t)f2b(q2.x)      | ((uint32_t)f2b(q2.y)      << 16);
  uint32_t ko = (uint32_t)f2b(q2.x * rs) | ((uint32_t)f2b(q2.y * rs) << 16);
  uint32_t vo = (uint32_t)f2b(v2.x)      | ((uint32_t)f2b(v2.y)      << 16);
  *(uint32_t*)(qb + off) = qo;
  *(uint32_t*)(kb + off) = ko;
  *(uint32_t*)(vb + off) = vo;
}

// Flash attention: 4 waves x 16 q-rows, KVBLK=64 per iteration.
__global__ __launch_bounds__(256, 2) void attn_kernel(
    const ushort* __restrict__ qb, const ushort* __restrict__ kb,
    const ushort* __restrict__ vb, float* __restrict__ out) {
  __shared__ ushort lds_k[KVBLK * DIM];        // row-major, XOR-swizzled 16B chunks
  __shared__ ushort lds_vt[DIM * VT_S];        // V transposed: [dcol][kv]
  __shared__ ushort lds_p[NWAVE * 16 * P_S];   // per-wave P staging

  const int tid = threadIdx.x;
  const int w = tid >> 6;
  const int l = tid & 63;
  const int g = l >> 4;     // lane group 0..3
  const int c = l & 15;     // lane-in-group 0..15

  const int bidx  = blockIdx.x;
  const int batch = bidx / (SEQN / QBLK);
  const int qt    = bidx % (SEQN / QBLK);
  const int q0    = qt * QBLK + w * 16;            // wave's first q row (in-batch)
  const size_t base = (size_t)batch * SEQN * DIM;

  // Q fragments: A[m=c][k=8g+j+32kc], 16B aligned global loads (one-time)
  bf16x8 qf[4];
  {
    const ushort* qp = qb + base + (size_t)(q0 + c) * DIM + g * 8;
    #pragma unroll
    for (int kc = 0; kc < 4; ++kc)
      qf[kc] = *(const bf16x8*)(qp + kc * 32);
  }

  f32x4 o[8];
  #pragma unroll
  for (int f = 0; f < 8; ++f) o[f] = (f32x4){0.f, 0.f, 0.f, 0.f};
  float mrow[4] = {-INFINITY, -INFINITY, -INFINITY, -INFINITY};
  float lrow[4] = {0.f, 0.f, 0.f, 0.f};

  const ushort* kb_b = kb + base;
  const ushort* vb_b = vb + base;

  for (int kt = 0; kt < SEQN / KVBLK; ++kt) {
    const int kv0 = kt * KVBLK;
    __syncthreads();
    // ---- stage K: 1024 x 16B chunks, chunk ^= (row&7) swizzle (bank-balanced) ----
    #pragma unroll
    for (int i = 0; i < 4; ++i) {
      int ch = tid + 256 * i;
      int r = ch >> 4, k = ch & 15;
      int4 d4 = *(const int4*)(kb_b + (size_t)(kv0 + r) * DIM + k * 8);
      *(int4*)(&lds_k[r * DIM + ((k ^ (r & 7)) << 3)]) = d4;
    }
    // ---- stage V transposed: pair-pack 2 kv rows -> dword columns, staggered ----
    #pragma unroll
    for (int i = 0; i < 2; ++i) {
      int s = tid + 256 * i;
      int p = s >> 4, k = s & 15;       // kv rows 2p,2p+1; dcols 8k..8k+7
      const ushort* va = vb_b + (size_t)(kv0 + 2 * p) * DIM + k * 8;
      uint64_t alo = ((const uint64_t*)va)[0];
      uint64_t ahi = ((const uint64_t*)va)[1];
      uint64_t blo = ((const uint64_t*)(va + DIM))[0];
      uint64_t bhi = ((const uint64_t*)(va + DIM))[1];
      #pragma unroll
      for (int e0 = 0; e0 < 8; ++e0) {
        int e = (e0 + k) & 7;           // stagger: avoids bank-group collision
        uint64_t as = (e & 4) ? ahi : alo;
        uint64_t bs = (e & 4) ? bhi : blo;
        int sh = (e & 3) * 16;
        uint32_t av = (uint32_t)(as >> sh) & 0xffffu;
        uint32_t bv = (uint32_t)(bs >> sh) & 0xffffu;
        *(uint32_t*)(&lds_vt[(8 * k + e) * VT_S + 2 * p]) = av | (bv << 16);
      }
    }
    __syncthreads();

    // ---- S = Q K'^T : 4 col-blocks x 4 k-chunks ----
    f32x4 sf[4];
    #pragma unroll
    for (int nb = 0; nb < 4; ++nb) {
      f32x4 acc = (f32x4){0.f, 0.f, 0.f, 0.f};
      #pragma unroll
      for (int kc = 0; kc < 4; ++kc) {
        int chunk = g + 4 * kc;
        int row = nb * 16 + c;
        bf16x8 kf = *(const bf16x8*)(&lds_k[row * DIM + ((chunk ^ (row & 7)) << 3)]);
        acc = __builtin_amdgcn_mfma_f32_16x16x32_bf16(qf[kc], kf, acc, 0, 0, 0);
      }
      sf[nb] = acc;
    }
    // ---- diagonal mask (wave-uniform branch) ----
    if (kv0 < q0 + 16 && q0 < kv0 + KVBLK) {
      #pragma unroll
      for (int nb = 0; nb < 4; ++nb)
        #pragma unroll
        for (int r = 0; r < 4; ++r)
          if (q0 + 4 * g + r == kv0 + nb * 16 + c) sf[nb][r] = -1e30f;
    }
    // ---- online softmax (base-2 domain; scale folded into K') ----
    float scl[4];
    #pragma unroll
    for (int r = 0; r < 4; ++r) {
      float mx = fmaxf(fmaxf(sf[0][r], sf[1][r]), fmaxf(sf[2][r], sf[3][r]));
      mx = fmaxf(mx, __shfl_xor(mx, 1, 64));
      mx = fmaxf(mx, __shfl_xor(mx, 2, 64));
      mx = fmaxf(mx, __shfl_xor(mx, 4, 64));
      mx = fmaxf(mx, __shfl_xor(mx, 8, 64));
      float mn = fmaxf(mrow[r], mx);
      scl[r] = exp2f(mrow[r] - mn);
      mrow[r] = mn;
    }
    float rsum[4] = {0.f, 0.f, 0.f, 0.f};
    #pragma unroll
    for (int nb = 0; nb < 4; ++nb)
      #pragma unroll
      for (int r = 0; r < 4; ++r) {
        float pv = exp2f(sf[nb][r] - mrow[r]);
        sf[nb][r] = pv;
        rsum[r] += pv;
      }
    #pragma unroll
    for (int r = 0; r < 4; ++r) {
      float v0 = rsum[r];
      v0 += __shfl_xor(v0, 1, 64);
      v0 += __shfl_xor(v0, 2, 64);
      v0 += __shfl_xor(v0, 4, 64);
      v0 += __shfl_xor(v0, 8, 64);
      lrow[r] = lrow[r] * scl[r] + v0;
    }
    #pragma unroll
    for (int f = 0; f < 8; ++f)
      #pragma unroll
      for (int r = 0; r < 4; ++r)
        o[f][r] *= scl[r];
    // ---- P -> LDS (bf16) -> A-frags (wave-local; no barrier needed) ----
    ushort* pw = &lds_p[w * 16 * P_S];
    #pragma unroll
    for (int nb = 0; nb < 4; ++nb)
      #pragma unroll
      for (int r = 0; r < 4; ++r)
        pw[(4 * g + r) * P_S + nb * 16 + c] = f2b(sf[nb][r]);
    bf16x8 pa[2];
    #pragma unroll
    for (int kc = 0; kc < 2; ++kc)
      pa[kc] = *(const bf16x8*)(&pw[c * P_S + kc * 32 + g * 8]);
    // ---- O += P V : 2 k-chunks x 8 d-blocks, Vt b64 reads (bank-balanced) ----
    #pragma unroll
    for (int kc = 0; kc < 2; ++kc) {
      #pragma unroll
      for (int nb = 0; nb < 8; ++nb) {
        union { uint64_t u[2]; bf16x8 v; } vv;
        const ushort* vp = &lds_vt[(nb * 16 + c) * VT_S + kc * 32 + g * 8];
        vv.u[0] = *(const uint64_t*)(vp);
        vv.u[1] = *(const uint64_t*)(vp + 4);
        o[nb] = __builtin_amdgcn_mfma_f32_16x16x32_bf16(pa[kc], vv.v, o[nb], 0, 0, 0);
      }
    }
  }

  // ---- epilogue: divide by l, fp32 store ----
  float inv[4];
  #pragma unroll
  for (int r = 0; r < 4; ++r) inv[r] = 1.0f / lrow[r];
  float* ob = out + base;
  #pragma unroll
  for (int nb = 0; nb < 8; ++nb)
    #pragma unroll
    for (int r = 0; r < 4; ++r)
      ob[(size_t)(q0 + 4 * g + r) * DIM + nb * 16 + c] = o[nb][r] * inv[r];
}

extern "C" void kernel_launch(void* const* d_in, const int* in_sizes, int n_in,
                              void* d_out, int out_size, void* d_ws, size_t ws_size,
                              hipStream_t stream) {
  (void)in_sizes; (void)n_in; (void)out_size; (void)ws_size;
  const float* qk = (const float*)d_in[0];
  const float* v  = (const float*)d_in[1];
  float* out = (float*)d_out;
  size_t nelem = (size_t)BATCH * SEQN * DIM;
  ushort* qb = (ushort*)d_ws;
  ushort* kb = qb + nelem;
  ushort* vb = kb + nelem;
  prep_kernel<<<BATCH * SEQN / NWAVE, 256, 0, stream>>>(qk, v, qb, kb, vb);
  attn_kernel<<<BATCH * (SEQN / QBLK), 256, 0, stream>>>(qb, kb, vb, out);
}

// Round 2
// 222.978 us; speedup vs baseline: 1.2017x; 1.2017x over previous
//
#include <hip/hip_runtime.h>
#include <hip/hip_bf16.h>
#include <stdint.h>

#define BATCH 8
#define SEQN  4096
#define DIM   128
#define KVB   64
#define NT    (SEQN / KVB)
#define QW    32              // q rows per wave
#define NW    4               // waves per block
#define QB    (QW * NW)       // 128 q rows per block
#define NWAVE 4               // prep kernel waves/block

#define VT_S 68               // Vt row stride (elems): 64 kv + 4 pad -> 2-way-free b64 reads
#define EP_S 34               // epilogue row stride (dwords): 32 + 2 pad

typedef __attribute__((ext_vector_type(4)))  float f32x4;
typedef __attribute__((ext_vector_type(16))) float f32x16;
typedef __bf16 bf16x8 __attribute__((ext_vector_type(8)));

__device__ __forceinline__ ushort f2b(float x) {
  union { float f; uint32_t u; } a; a.f = x;
  uint32_t r = a.u + 0x7fffu + ((a.u >> 16) & 1u);   // RNE
  return (ushort)(r >> 16);
}

__device__ __forceinline__ uint32_t pkbf(float a, float b) {
  union { __bf16 h[2]; uint32_t u; } x;
  x.h[0] = (__bf16)a; x.h[1] = (__bf16)b;
  return x.u;
}

// One wave per row: rnorm + bf16 casts. K' = qk * rnorm * log2(e)/sqrt(d)
__global__ __launch_bounds__(256) void prep_kernel(
    const float* __restrict__ qk, const float* __restrict__ v,
    ushort* __restrict__ qb, ushort* __restrict__ kb, ushort* __restrict__ vb) {
  int row  = blockIdx.x * NWAVE + (threadIdx.x >> 6);
  int lane = threadIdx.x & 63;
  size_t off = (size_t)row * DIM + lane * 2;
  float2 q2 = *(const float2*)(qk + off);
  float2 v2 = *(const float2*)(v + off);
  float ss = q2.x * q2.x + q2.y * q2.y;
  #pragma unroll
  for (int m = 32; m; m >>= 1) ss += __shfl_xor(ss, m, 64);
  float nrm = sqrtf(ss);
  float r = 1.0f / fmaxf(nrm, 1e-12f);
  const float SC = 1.44269504088896340736f / 11.313708498984761f; // log2e/sqrt(128)
  float rs = r * SC;
  uint32_t qo = (uint32_t)f2b(q2.x)      | ((uint32_t)f2b(q2.y)      << 16);
  uint32_t ko = (uint32_t)f2b(q2.x * rs) | ((uint32_t)f2b(q2.y * rs) << 16);
  uint32_t vo = (uint32_t)f2b(v2.x)      | ((uint32_t)f2b(v2.y)      << 16);
  *(uint32_t*)(qb + off) = qo;
  *(uint32_t*)(kb + off) = ko;
  *(uint32_t*)(vb + off) = vo;
}

// Swapped-QK flash attention: 4 waves x 32 q-rows, 32x32x16 MFMA, O^T accumulation.
__global__ __launch_bounds__(256, 1) void attn_kernel(
    const ushort* __restrict__ qb, const ushort* __restrict__ kb,
    const ushort* __restrict__ vb, float* __restrict__ out) {
  __shared__ ushort lds_k[KVB * DIM];          // K row-major, 16B-chunk XOR swizzle
  __shared__ ushort lds_vt[DIM * VT_S];        // V transposed: [d][kv]
  __shared__ float  lds_ep[NW * QW * EP_S];    // per-wave epilogue transpose (one d-block)

  const int tid = threadIdx.x;
  const int w  = tid >> 6;
  const int l  = tid & 63;
  const int ql = l & 31;       // q column (and d row for V^T frags)
  const int hi = l >> 5;

  // XCD swizzle: batch b -> XCD b (its 32 blocks share the 2MB KV in one L2)
  const int bidx = blockIdx.x;
  const int swz  = (bidx & 7) * 32 + (bidx >> 3);
  const int batch = swz >> 5;
  const int qt    = swz & 31;
  const int q0W   = qt * QB + w * QW;
  const size_t base = (size_t)batch * SEQN * DIM;

  // Q fragments (B-operand of S^T = K*Q^T): lane holds Q[q0W+ql][16kc+8hi+j]
  bf16x8 qf[8];
  {
    const ushort* qp = qb + base + (size_t)(q0W + ql) * DIM + hi * 8;
    #pragma unroll
    for (int kc = 0; kc < 8; ++kc) qf[kc] = *(const bf16x8*)(qp + kc * 16);
  }

  f32x16 o[4];
  #pragma unroll
  for (int db = 0; db < 4; ++db)
    #pragma unroll
    for (int r = 0; r < 16; ++r) o[db][r] = 0.f;
  float m = -INFINITY, lsum = 0.f;

  const ushort* kb_b = kb + base;
  const ushort* vb_b = vb + base;

  // ---- prologue: stage tile 0 ----
  {
    int4 kr[4]; uint64_t vr[8];
    #pragma unroll
    for (int i = 0; i < 4; ++i) {
      int n = tid + 256 * i, r = n >> 4, c = n & 15;
      kr[i] = *(const int4*)(kb_b + (size_t)r * DIM + c * 8);
    }
    #pragma unroll
    for (int i = 0; i < 2; ++i) {
      int s = tid + 256 * i, p = s >> 4, k = s & 15;
      const ushort* va = vb_b + (size_t)(2 * p) * DIM + k * 8;
      vr[4*i+0] = ((const uint64_t*)va)[0];
      vr[4*i+1] = ((const uint64_t*)va)[1];
      vr[4*i+2] = ((const uint64_t*)(va + DIM))[0];
      vr[4*i+3] = ((const uint64_t*)(va + DIM))[1];
    }
    #pragma unroll
    for (int i = 0; i < 4; ++i) {
      int n = tid + 256 * i, r = n >> 4, c = n & 15;
      *(int4*)((char*)lds_k + r * 256 + ((c ^ (r & 7)) << 4)) = kr[i];
    }
    #pragma unroll
    for (int i = 0; i < 2; ++i) {
      int s = tid + 256 * i, p = s >> 4, k = s & 15;
      uint64_t alo = vr[4*i], ahi = vr[4*i+1], blo = vr[4*i+2], bhi = vr[4*i+3];
      #pragma unroll
      for (int e0 = 0; e0 < 8; ++e0) {
        int e = (e0 + k) & 7;
        uint64_t as = (e & 4) ? ahi : alo, bs = (e & 4) ? bhi : blo;
        int sh = (e & 3) * 16;
        uint32_t av = (uint32_t)(as >> sh) & 0xffffu, bv = (uint32_t)(bs >> sh) & 0xffffu;
        *(uint32_t*)(&lds_vt[(8 * k + e) * VT_S + 2 * p]) = av | (bv << 16);
      }
    }
  }
  __syncthreads();

  int4 kr[4]; uint64_t vr[8];
  for (int kt = 0; kt < NT; ++kt) {
    const int kv0 = kt * KVB;
    const bool pf = (kt + 1 < NT);
    // ---- T14: issue next tile's global loads before compute ----
    if (pf) {
      const int kvn = kv0 + KVB;
      #pragma unroll
      for (int i = 0; i < 4; ++i) {
        int n = tid + 256 * i, r = n >> 4, c = n & 15;
        kr[i] = *(const int4*)(kb_b + (size_t)(kvn + r) * DIM + c * 8);
      }
      #pragma unroll
      for (int i = 0; i < 2; ++i) {
        int s = tid + 256 * i, p = s >> 4, k = s & 15;
        const ushort* va = vb_b + (size_t)(kvn + 2 * p) * DIM + k * 8;
        vr[4*i+0] = ((const uint64_t*)va)[0];
        vr[4*i+1] = ((const uint64_t*)va)[1];
        vr[4*i+2] = ((const uint64_t*)(va + DIM))[0];
        vr[4*i+3] = ((const uint64_t*)(va + DIM))[1];
      }
    }

    // ---- S^T = K * Q^T : 2 kv 32-blocks x 8 k-chunks ----
    f32x16 st[2];
    #pragma unroll
    for (int n2 = 0; n2 < 2; ++n2) {
      #pragma unroll
      for (int r = 0; r < 16; ++r) st[n2][r] = 0.f;
      #pragma unroll
      for (int kc = 0; kc < 8; ++kc) {
        const int row = 32 * n2 + ql;
        const int chunk = 2 * kc + hi;
        const bf16x8 kf =
            *(const bf16x8*)((const char*)lds_k + row * 256 + ((chunk ^ (ql & 7)) << 4));
        st[n2] = __builtin_amdgcn_mfma_f32_32x32x16_bf16(kf, qf[kc], st[n2], 0, 0, 0);
      }
    }

    // ---- diagonal mask (wave-uniform branch: q-tile inside exactly one kv-tile) ----
    if ((q0W & ~(KVB - 1)) == kv0) {
      const int dloc = q0W + ql - kv0;   // masked kv_local for this lane's q row
      #pragma unroll
      for (int n2 = 0; n2 < 2; ++n2)
        #pragma unroll
        for (int r = 0; r < 16; ++r) {
          int crow = (r & 3) + 8 * (r >> 2) + 4 * hi + 32 * n2;
          if (crow == dloc) st[n2][r] = -1e30f;
        }
    }

    // ---- in-register online softmax (lane owns q = q0W + ql) ----
    float pm = st[0][0];
    #pragma unroll
    for (int r = 1; r < 16; ++r) pm = fmaxf(pm, st[0][r]);
    #pragma unroll
    for (int r = 0; r < 16; ++r) pm = fmaxf(pm, st[1][r]);
    pm = fmaxf(pm, __shfl_xor(pm, 32, 64));
    if (__any(pm > m + 8.0f)) {          // T13 defer-max, THR=8
      float mn = fmaxf(m, pm);
      float sc = exp2f(m - mn);
      m = mn; lsum *= sc;
      #pragma unroll
      for (int db = 0; db < 4; ++db)
        #pragma unroll
        for (int r = 0; r < 16; ++r) o[db][r] *= sc;
    }
    float rs = 0.f;
    #pragma unroll
    for (int n2 = 0; n2 < 2; ++n2)
      #pragma unroll
      for (int r = 0; r < 16; ++r) {
        float p = exp2f(st[n2][r] - m);
        st[n2][r] = p;
        rs += p;
      }
    rs += __shfl_xor(rs, 32, 64);
    lsum += rs;

    // ---- pack P -> bf16 words; quad-exchange across halves (T12 via shfl) ----
    uint32_t ww[2][4][2];
    #pragma unroll
    for (int n2 = 0; n2 < 2; ++n2)
      #pragma unroll
      for (int q = 0; q < 4; ++q) {
        ww[n2][q][0] = pkbf(st[n2][4 * q + 0], st[n2][4 * q + 1]);
        ww[n2][q][1] = pkbf(st[n2][4 * q + 2], st[n2][4 * q + 3]);
      }
    bf16x8 pa[4];
    #pragma unroll
    for (int ks = 0; ks < 4; ++ks) {
      const int n2 = ks >> 1, kk = ks & 1;
      uint32_t ow0 = hi ? ww[n2][2*kk+1][0] : ww[n2][2*kk][0];
      uint32_t ow1 = hi ? ww[n2][2*kk+1][1] : ww[n2][2*kk][1];
      uint32_t sv0 = hi ? ww[n2][2*kk][0]   : ww[n2][2*kk+1][0];
      uint32_t sv1 = hi ? ww[n2][2*kk][1]   : ww[n2][2*kk+1][1];
      uint32_t rv0 = (uint32_t)__shfl_xor((int)sv0, 32, 64);
      uint32_t rv1 = (uint32_t)__shfl_xor((int)sv1, 32, 64);
      union { uint32_t u[4]; bf16x8 v; } pb;
      pb.u[0] = hi ? rv0 : ow0;
      pb.u[1] = hi ? rv1 : ow1;
      pb.u[2] = hi ? ow0 : rv0;
      pb.u[3] = hi ? ow1 : rv1;
      pa[ks] = pb.v;
    }

    // ---- O^T += V^T * P^T : 4 d-blocks x 4 kv-chunks ----
    #pragma unroll
    for (int db = 0; db < 4; ++db)
      #pragma unroll
      for (int ks = 0; ks < 4; ++ks) {
        const ushort* vp = lds_vt + (32 * db + ql) * VT_S + 16 * ks + 8 * hi;
        union { uint64_t u[2]; bf16x8 v; } vv;
        vv.u[0] = *(const uint64_t*)(vp);
        vv.u[1] = *(const uint64_t*)(vp + 4);
        o[db] = __builtin_amdgcn_mfma_f32_32x32x16_bf16(vv.v, pa[ks], o[db], 0, 0, 0);
      }

    __syncthreads();
    // ---- write-late: LDS staging of tile t+1 ----
    if (pf) {
      #pragma unroll
      for (int i = 0; i < 4; ++i) {
        int n = tid + 256 * i, r = n >> 4, c = n & 15;
        *(int4*)((char*)lds_k + r * 256 + ((c ^ (r & 7)) << 4)) = kr[i];
      }
      #pragma unroll
      for (int i = 0; i < 2; ++i) {
        int s = tid + 256 * i, p = s >> 4, k = s & 15;
        uint64_t alo = vr[4*i], ahi = vr[4*i+1], blo = vr[4*i+2], bhi = vr[4*i+3];
        #pragma unroll
        for (int e0 = 0; e0 < 8; ++e0) {
          int e = (e0 + k) & 7;
          uint64_t as = (e & 4) ? ahi : alo, bs = (e & 4) ? bhi : blo;
          int sh = (e & 3) * 16;
          uint32_t av = (uint32_t)(as >> sh) & 0xffffu, bv = (uint32_t)(bs >> sh) & 0xffffu;
          *(uint32_t*)(&lds_vt[(8 * k + e) * VT_S + 2 * p]) = av | (bv << 16);
        }
      }
    }
    __syncthreads();
  }

  // ---- epilogue: per-wave LDS transpose per d-block, coalesced float2 stores ----
  const float inv = 1.0f / lsum;
  float* epw = lds_ep + w * QW * EP_S;
  float* outb = out + base;
  #pragma unroll
  for (int db = 0; db < 4; ++db) {
    #pragma unroll
    for (int rr = 0; rr < 8; ++rr) {
      const int r0 = 2 * rr;
      const int crow = (r0 & 3) + 8 * (r0 >> 2) + 4 * hi;
      float2 v2 = make_float2(o[db][r0] * inv, o[db][r0 + 1] * inv);
      *(float2*)(epw + ql * EP_S + crow) = v2;
    }
    __builtin_amdgcn_s_waitcnt(0);  // ensure wave's LDS writes land before cross-lane reads
    #pragma unroll
    for (int s = 0; s < 8; ++s) {
      const int row = 4 * s + (l >> 4);
      const int c2  = l & 15;
      float2 v2 = *(const float2*)(epw + row * EP_S + 2 * c2);
      *(float2*)(outb + (size_t)(q0W + row) * DIM + 32 * db + 2 * c2) = v2;
    }
    __builtin_amdgcn_s_waitcnt(0);  // reads done before next db overwrites
  }
}

extern "C" void kernel_launch(void* const* d_in, const int* in_sizes, int n_in,
                              void* d_out, int out_size, void* d_ws, size_t ws_size,
                              hipStream_t stream) {
  (void)in_sizes; (void)n_in; (void)out_size; (void)ws_size;
  const float* qk = (const float*)d_in[0];
  const float* v  = (const float*)d_in[1];
  float* out = (float*)d_out;
  size_t nelem = (size_t)BATCH * SEQN * DIM;
  ushort* qb = (ushort*)d_ws;
  ushort* kb = qb + nelem;
  ushort* vb = kb + nelem;
  prep_kernel<<<BATCH * SEQN / NWAVE, 256, 0, stream>>>(qk, v, qb, kb, vb);
  attn_kernel<<<BATCH * (SEQN / QB), 256, 0, stream>>>(qb, kb, vb, out);
}

// Round 3
// 120.476 us; speedup vs baseline: 2.2242x; 1.8508x over previous
//
#include <hip/hip_runtime.h>
#include <hip/hip_bf16.h>
#include <stdint.h>

#define BATCH 8
#define SEQN  4096
#define DIM   128
#define KVB   64
#define HALF  2048
#define NTH   (HALF / KVB)    // 32 iterations per half
#define QW    32              // q rows per wave
#define QB    128             // q rows per block (4 chunks x 32)
#define EP_S  34              // epilogue transpose row stride (floats)

typedef __attribute__((ext_vector_type(16))) float f32x16;
typedef __bf16 bf16x8 __attribute__((ext_vector_type(8)));

#define GAS __attribute__((address_space(1)))
#define LAS __attribute__((address_space(3)))

__device__ __forceinline__ ushort f2b(float x) {
  union { float f; uint32_t u; } a; a.f = x;
  uint32_t r = a.u + 0x7fffu + ((a.u >> 16) & 1u);   // RNE
  return (ushort)(r >> 16);
}
__device__ __forceinline__ uint32_t pkbf(float a, float b) {
  union { __bf16 h[2]; uint32_t u; } x;
  x.h[0] = (__bf16)a; x.h[1] = (__bf16)b;
  return x.u;
}

// One wave per row: Q plain bf16; K' = qk*rnorm*log2e/sqrt(d), chunk-XOR-swizzled
// within each 256B row so attn can global_load_lds linearly (m173 pattern).
__global__ __launch_bounds__(256) void prep_kernel(
    const float* __restrict__ qk, ushort* __restrict__ qb, ushort* __restrict__ kb) {
  int row  = blockIdx.x * 4 + (threadIdx.x >> 6);
  int ln   = threadIdx.x & 63;
  size_t roff = (size_t)row * DIM;
  float2 q2 = *(const float2*)(qk + roff + ln * 2);
  float ss = q2.x * q2.x + q2.y * q2.y;
  #pragma unroll
  for (int m = 32; m; m >>= 1) ss += __shfl_xor(ss, m, 64);
  float r = 1.0f / fmaxf(sqrtf(ss), 1e-12f);
  const float SC = 1.44269504088896340736f / 11.313708498984761f; // log2e/sqrt(128)
  float rs = r * SC;
  *(uint32_t*)(qb + roff + ln * 2) =
      (uint32_t)f2b(q2.x) | ((uint32_t)f2b(q2.y) << 16);
  int ch = ln >> 2;                       // 16B chunk 0..15
  int pos = ((ch ^ (row & 7)) << 3) + (ln & 3) * 2;
  *(uint32_t*)(kb + roff + pos) =
      (uint32_t)f2b(q2.x * rs) | ((uint32_t)f2b(q2.y * rs) << 16);
}

// One-time V transpose: 64kv x 128d f32 tile -> bf16 [128][64] pre-swizzled tile.
__global__ __launch_bounds__(256) void vtrans_kernel(
    const float* __restrict__ v, ushort* __restrict__ vt) {
  __shared__ ushort t[64][136];
  int tile = blockIdx.x;                  // batch*64 + kvtile
  const float* src = v + (size_t)tile * KVB * DIM;
  int tid = threadIdx.x;
  #pragma unroll
  for (int i = 0; i < 8; ++i) {
    int n = tid + 256 * i;                // float4 index 0..2047
    int r = n >> 5, c4 = n & 31;
    float4 f = *(const float4*)(src + r * DIM + 4 * c4);
    *(uint32_t*)&t[r][4 * c4]     = pkbf(f.x, f.y);
    *(uint32_t*)&t[r][4 * c4 + 2] = pkbf(f.z, f.w);
  }
  __syncthreads();
  ushort* dst = vt + (size_t)tile * 8192;
  #pragma unroll
  for (int i = 0; i < 4; ++i) {
    int n = tid + 256 * i;                // chunk index 0..1023
    int d = n >> 3, c = n & 7;
    ushort tmp[8];
    #pragma unroll
    for (int j = 0; j < 8; ++j) tmp[j] = t[8 * c + j][d];
    *(int4*)(dst + d * 64 + ((c ^ (d & 7)) << 3)) = *(int4*)tmp;
  }
}

// 8 waves: waves 0-3 -> KV[0,2048), waves 4-7 -> KV[2048,4096); LDS combine.
__global__ __launch_bounds__(512, 2) void attn_kernel(
    const ushort* __restrict__ qb, const ushort* __restrict__ kb,
    const ushort* __restrict__ vt, float* __restrict__ out) {
  __shared__ ushort lds_all[65536];       // 128KB: [2 buf][K0,K1,V0,V1][8192]

  const int tid = threadIdx.x;
  const int w  = tid >> 6;
  const int l  = tid & 63;
  const int ql = l & 31;
  const int hi = l >> 5;
  const int qc = w & 3;                   // q chunk
  const int hf = w >> 2;                  // kv half

  const int bidx  = blockIdx.x;
  const int batch = bidx & 7;             // XCD b gets batch b
  const int qt    = bidx >> 3;
  const int q0W   = qt * QB + qc * QW;
  const size_t base = (size_t)batch * SEQN * DIM;

  const ushort* kb_b = kb + base;
  const ushort* vt_b = vt + base;         // [64 tiles][8192] per batch

  // Q fragments: lane holds Q[q0W+ql][16kc+8hi+j]
  bf16x8 qf[8];
  {
    const ushort* qp = qb + base + (size_t)(q0W + ql) * DIM + hi * 8;
    #pragma unroll
    for (int kc = 0; kc < 8; ++kc) qf[kc] = *(const bf16x8*)(qp + kc * 16);
  }

  f32x16 o[4];
  #pragma unroll
  for (int db = 0; db < 4; ++db)
    #pragma unroll
    for (int r = 0; r < 16; ++r) o[db][r] = 0.f;
  float m = -INFINITY, lsum = 0.f;

  const int tT  = w >> 1;                 // staging tile: 0=K0 1=K1 2=V0 3=V1
  const int sub = w & 1;

#define STAGE(bsel, kt_) do {                                                  \
    const ushort* srcs_;                                                       \
    if      (tT == 0) srcs_ = kb_b + (size_t)((kt_) * KVB) * DIM;              \
    else if (tT == 1) srcs_ = kb_b + (size_t)(HALF + (kt_) * KVB) * DIM;       \
    else if (tT == 2) srcs_ = vt_b + (size_t)(kt_) * 8192;                     \
    else              srcs_ = vt_b + (size_t)(32 + (kt_)) * 8192;              \
    ushort* dbase_ = lds_all + (bsel) * 32768 + tT * 8192 + sub * 4096;        \
    const ushort* sbase_ = srcs_ + sub * 4096 + l * 8;                         \
    _Pragma("unroll")                                                          \
    for (int i_ = 0; i_ < 8; ++i_)                                             \
      __builtin_amdgcn_global_load_lds((const GAS uint32_t*)(sbase_ + i_*512), \
                                       (LAS uint32_t*)(dbase_ + i_*512),       \
                                       16, 0, 0);                              \
  } while (0)

  // prologue
  STAGE(0, 0);
  asm volatile("s_waitcnt vmcnt(0)" ::: "memory");
  __syncthreads();

  int buf = 0;
  for (int kt = 0; kt < NTH; ++kt) {
    if (kt + 1 < NTH) STAGE(buf ^ 1, kt + 1);
    const int kv0 = hf * HALF + kt * KVB;
    const ushort* kbase = lds_all + buf * 32768 + hf * 8192;
    const ushort* vbase = lds_all + buf * 32768 + 16384 + hf * 8192;

    // ---- S^T = K * Q^T ----
    f32x16 st[2];
    __builtin_amdgcn_s_setprio(1);
    #pragma unroll
    for (int n2 = 0; n2 < 2; ++n2) {
      #pragma unroll
      for (int r = 0; r < 16; ++r) st[n2][r] = 0.f;
      #pragma unroll
      for (int kc = 0; kc < 8; ++kc) {
        const int row = 32 * n2 + ql;
        const int chunk = (2 * kc + hi) ^ (ql & 7);
        const bf16x8 kf = *(const bf16x8*)(kbase + row * 128 + (chunk << 3));
        st[n2] = __builtin_amdgcn_mfma_f32_32x32x16_bf16(kf, qf[kc], st[n2], 0, 0, 0);
      }
    }
    __builtin_amdgcn_s_setprio(0);

    // ---- diagonal mask ----
    if ((q0W & ~(KVB - 1)) == kv0) {
      const int dloc = q0W + ql - kv0;
      #pragma unroll
      for (int n2 = 0; n2 < 2; ++n2)
        #pragma unroll
        for (int r = 0; r < 16; ++r) {
          int crow = (r & 3) + 8 * (r >> 2) + 4 * hi + 32 * n2;
          if (crow == dloc) st[n2][r] = -1e30f;
        }
    }

    // ---- online softmax (lane owns q-row ql) ----
    float pm = st[0][0];
    #pragma unroll
    for (int r = 1; r < 16; ++r) pm = fmaxf(pm, st[0][r]);
    #pragma unroll
    for (int r = 0; r < 16; ++r) pm = fmaxf(pm, st[1][r]);
    pm = fmaxf(pm, __shfl_xor(pm, 32, 64));
    if (__any(pm > m + 8.0f)) {           // T13 defer-max
      float mn = fmaxf(m, pm);
      float sc = exp2f(m - mn);
      m = mn; lsum *= sc;
      #pragma unroll
      for (int db = 0; db < 4; ++db)
        #pragma unroll
        for (int r = 0; r < 16; ++r) o[db][r] *= sc;
    }
    float rs = 0.f;
    #pragma unroll
    for (int n2 = 0; n2 < 2; ++n2)
      #pragma unroll
      for (int r = 0; r < 16; ++r) {
        float p = exp2f(st[n2][r] - m);
        st[n2][r] = p;
        rs += p;
      }
    rs += __shfl_xor(rs, 32, 64);
    lsum += rs;

    // ---- pack P -> bf16; quad exchange across halves ----
    uint32_t ww[2][4][2];
    #pragma unroll
    for (int n2 = 0; n2 < 2; ++n2)
      #pragma unroll
      for (int q = 0; q < 4; ++q) {
        ww[n2][q][0] = pkbf(st[n2][4 * q + 0], st[n2][4 * q + 1]);
        ww[n2][q][1] = pkbf(st[n2][4 * q + 2], st[n2][4 * q + 3]);
      }
    bf16x8 pa[4];
    #pragma unroll
    for (int ks = 0; ks < 4; ++ks) {
      const int n2 = ks >> 1, kk = ks & 1;
      uint32_t ow0 = hi ? ww[n2][2*kk+1][0] : ww[n2][2*kk][0];
      uint32_t ow1 = hi ? ww[n2][2*kk+1][1] : ww[n2][2*kk][1];
      uint32_t sv0 = hi ? ww[n2][2*kk][0]   : ww[n2][2*kk+1][0];
      uint32_t sv1 = hi ? ww[n2][2*kk][1]   : ww[n2][2*kk+1][1];
      uint32_t rv0 = (uint32_t)__shfl_xor((int)sv0, 32, 64);
      uint32_t rv1 = (uint32_t)__shfl_xor((int)sv1, 32, 64);
      union { uint32_t u[4]; bf16x8 v; } pb;
      pb.u[0] = hi ? rv0 : ow0;
      pb.u[1] = hi ? rv1 : ow1;
      pb.u[2] = hi ? ow0 : rv0;
      pb.u[3] = hi ? ow1 : rv1;
      pa[ks] = pb.v;
    }

    // ---- O^T += V^T * P^T ----
    __builtin_amdgcn_s_setprio(1);
    #pragma unroll
    for (int db = 0; db < 4; ++db)
      #pragma unroll
      for (int ks = 0; ks < 4; ++ks) {
        const int row = 32 * db + ql;
        const int chunk = (2 * ks + hi) ^ (ql & 7);
        const bf16x8 vv = *(const bf16x8*)(vbase + row * 64 + (chunk << 3));
        o[db] = __builtin_amdgcn_mfma_f32_32x32x16_bf16(vv, pa[ks], o[db], 0, 0, 0);
      }
    __builtin_amdgcn_s_setprio(0);

    asm volatile("s_waitcnt vmcnt(0)" ::: "memory");
    __syncthreads();
    buf ^= 1;
  }
#undef STAGE

  // ---- combine halves through LDS ----
  float* fl = (float*)lds_all;            // [8 waves][64]: m, l
  if (hi == 0) { fl[w * 64 + ql] = m; fl[w * 64 + 32 + ql] = lsum; }
  __syncthreads();
  const int pw = w ^ 4;
  float m_o = fl[pw * 64 + ql];
  float l_o = fl[pw * 64 + 32 + ql];
  float M = fmaxf(m, m_o);
  float sc_self = exp2f(m - M);
  float l_tot = lsum * sc_self + l_o * exp2f(m_o - M);

  float* oreg = (float*)lds_all + 1024 + qc * 4096;  // [32 q][128 d] per q-chunk
  if (hf == 1) {
    #pragma unroll
    for (int db = 0; db < 4; ++db)
      #pragma unroll
      for (int r = 0; r < 16; ++r) {
        int crow = (r & 3) + 8 * (r >> 2) + 4 * hi;
        oreg[crow * 128 + 32 * db + ql] = o[db][r] * sc_self;
      }
  }
  __syncthreads();
  if (hf == 0) {
    const float inv = 1.0f / l_tot;
    #pragma unroll
    for (int db = 0; db < 4; ++db)
      #pragma unroll
      for (int r = 0; r < 16; ++r) {
        int crow = (r & 3) + 8 * (r >> 2) + 4 * hi;
        o[db][r] = (o[db][r] * sc_self + oreg[crow * 128 + 32 * db + ql]) * inv;
      }
    // per-wave transpose -> coalesced stores
    float* epw = (float*)lds_all + 17408 + w * (QW * EP_S);
    float* outb = out + base;
    #pragma unroll
    for (int db = 0; db < 4; ++db) {
      #pragma unroll
      for (int rr = 0; rr < 8; ++rr) {
        const int r0 = 2 * rr;
        const int crow = (r0 & 3) + 8 * (r0 >> 2) + 4 * hi;
        *(float2*)(epw + ql * EP_S + crow) = make_float2(o[db][r0], o[db][r0 + 1]);
      }
      __builtin_amdgcn_s_waitcnt(0);
      #pragma unroll
      for (int s = 0; s < 8; ++s) {
        const int row = 4 * s + (l >> 4);
        const int c2  = l & 15;
        float2 v2 = *(const float2*)(epw + row * EP_S + 2 * c2);
        *(float2*)(outb + (size_t)(q0W + row) * DIM + 32 * db + 2 * c2) = v2;
      }
      __builtin_amdgcn_s_waitcnt(0);
    }
  }
}

extern "C" void kernel_launch(void* const* d_in, const int* in_sizes, int n_in,
                              void* d_out, int out_size, void* d_ws, size_t ws_size,
                              hipStream_t stream) {
  (void)in_sizes; (void)n_in; (void)out_size; (void)ws_size;
  const float* qk = (const float*)d_in[0];
  const float* v  = (const float*)d_in[1];
  float* out = (float*)d_out;
  size_t nelem = (size_t)BATCH * SEQN * DIM;
  ushort* qb = (ushort*)d_ws;
  ushort* kb = qb + nelem;
  ushort* vt = kb + nelem;
  prep_kernel<<<BATCH * SEQN / 4, 256, 0, stream>>>(qk, qb, kb);
  vtrans_kernel<<<BATCH * (SEQN / KVB), 256, 0, stream>>>(v, vt);
  attn_kernel<<<BATCH * (SEQN / QB), 512, 0, stream>>>(qb, kb, vt, out);
}